// Round 4
// baseline (106268.469 us; speedup 1.0000x reference)
//
#include <hip/hip_runtime.h>
#include <hip/hip_bf16.h>

#define BB 256
#define TT 2000
#define FF 42
#define HVAD 24
#define HNOI 48
#define HDEN 96
#define NTHREADS 384

__device__ __forceinline__ float bf2f(__hip_bfloat16 v) { return __bfloat162float(v); }
__device__ __forceinline__ float sig(float x) { return 1.0f / (1.0f + __expf(-x)); }
__device__ __forceinline__ float tanh_fast(float x) {
    float e = __expf(2.0f * x);
    return 1.0f - 2.0f / (e + 1.0f);
}
__device__ __forceinline__ float unpk_lo(unsigned u) {
    union { unsigned u; float f; } c; c.u = u << 16; return c.f;
}
__device__ __forceinline__ float unpk_hi(unsigned u) {
    union { unsigned u; float f; } c; c.u = u & 0xffff0000u; return c.f;
}
// fp32 -> bf16 bits, round-to-nearest-even
__device__ __forceinline__ unsigned f2bfbits(float f) {
    union { float f; unsigned u; } c; c.f = f;
    unsigned r = c.u + 0x7FFFu + ((c.u >> 16) & 1u);
    return r >> 16;
}
__device__ __forceinline__ unsigned pack2(float a, float b) {
    return f2bfbits(a) | (f2bfbits(b) << 16);
}
__device__ __forceinline__ float gload(const void* p, int i, bool f32) {
    return f32 ? ((const float*)p)[i] : bf2f(((const __hip_bfloat16*)p)[i]);
}

// W[O][K] row-major, K even -> packed bf16 pairs transposed:
// dst[kp*O + o] holds (W[o][2kp], W[o][2kp+1]).  Kw = K/2.
__device__ __forceinline__ void load_Tp(unsigned* dst, const void* src,
                                        int O, int Kw, int tid, int nt, bool f32) {
    for (int i = tid; i < O * Kw; i += nt) {
        int o = i / Kw, kp = i % Kw;
        unsigned w;
        if (f32) {
            const float* s = (const float*)src;
            w = pack2(s[2 * i], s[2 * i + 1]);
        } else {
            w = ((const unsigned*)src)[i];
        }
        dst[kp * O + o] = w;
    }
}
// W[O][K] row-major -> fp32 transposed dst[k*O + o]
__device__ __forceinline__ void load_T(float* dst, const void* src,
                                       int O, int K, int tid, int nt, bool f32) {
    for (int i = tid; i < O * K; i += nt) {
        int o = i / K, k = i % K;
        dst[k * O + o] = gload(src, i, f32);
    }
}
__device__ __forceinline__ void load_V(float* dst, const void* src,
                                       int n, int tid, int nt, bool f32) {
    for (int i = tid; i < n; i += nt) dst[i] = gload(src, i, f32);
}

__global__ __launch_bounds__(NTHREADS, 1)
void rnn_fused(const void* __restrict__ x,
               const void* __restrict__ dense_w,
               const void* __restrict__ dense_b,
               const void* __restrict__ vad_w_ih,
               const void* __restrict__ vad_w_hh,
               const void* __restrict__ vad_b_ih,
               const void* __restrict__ vad_b_hh,
               const void* __restrict__ vad_out_w,
               const void* __restrict__ vad_out_b,
               const void* __restrict__ noise_w_ih,
               const void* __restrict__ noise_w_hh,
               const void* __restrict__ noise_b_ih,
               const void* __restrict__ noise_b_hh,
               const void* __restrict__ den_w_ih,
               const void* __restrict__ den_w_hh,
               const void* __restrict__ den_b_ih,
               const void* __restrict__ den_b_hh,
               const void* __restrict__ out_w,
               const void* __restrict__ out_b,
               void* __restrict__ d_out) {
    // ---- LDS (~62.5 KiB, under the 64 KiB workgroup limit) ----
    __shared__ unsigned sVIHp[12 * 72];
    __shared__ unsigned sVHHp[12 * 72];
    __shared__ unsigned sNIHp[45 * 144];
    __shared__ unsigned sNHHp[24 * 144];
    __shared__ unsigned sOWp[48 * 22];
    __shared__ float sDW[42 * 24];
    __shared__ float sDB[24];
    __shared__ float sVBI[72], sVBH[72], sVOW[24], sVOB[1];
    __shared__ float sNBI[144], sNBH[144];
    __shared__ float sDBI[288], sDBH[288];
    __shared__ float sOB[22];
    __shared__ float sXT[FF];
    __shared__ float sTMP[HVAD];
    __shared__ float sHV[HVAD], sHN[HNOI], sHD[HDEN];
    __shared__ float sNIN[90];            // [tmp, vad, x]
    __shared__ float sDIN[114];           // [vad, relu(noise), x]
    __shared__ float sR[96], sZ[96], sXN[96], sHN2[96];
    __shared__ int sBad;

    const int tid = threadIdx.x;
    const int b = blockIdx.x;
    const int nt = NTHREADS;

    // ---- dtype detection (bf16 vs fp32 storage) ----
    if (tid == 0) sBad = 0;
    __syncthreads();
    {
        const unsigned* w = (const unsigned*)dense_w;
        for (int i = tid; i < 500; i += nt) {
            float av = fabsf(unpk_lo(w[i]));
            if (!(av <= 1e3f)) { atomicAdd(&sBad, 1); break; }
        }
    }
    __syncthreads();
    const bool F32 = (sBad > 0);

    const float* xbf = (const float*)x + (size_t)b * TT * FF;
    const __hip_bfloat16* xbh = (const __hip_bfloat16*)x + (size_t)b * TT * FF;
    float* odf = (float*)d_out;
    __hip_bfloat16* odh = (__hip_bfloat16*)d_out;
    float* ovf = odf + (size_t)BB * TT * 22;
    __hip_bfloat16* ovh = odh + (size_t)BB * TT * 22;

    // ---- load weights ----
    load_T (sDW,  dense_w,   24, 42, tid, nt, F32);
    load_V (sDB,  dense_b,   24, tid, nt, F32);
    load_Tp(sVIHp, vad_w_ih, 72, 12, tid, nt, F32);
    load_Tp(sVHHp, vad_w_hh, 72, 12, tid, nt, F32);
    load_V (sVBI, vad_b_ih,  72, tid, nt, F32);
    load_V (sVBH, vad_b_hh,  72, tid, nt, F32);
    load_V (sVOW, vad_out_w, 24, tid, nt, F32);
    if (tid == 0) sVOB[0] = gload(vad_out_b, 0, F32);
    load_Tp(sNIHp, noise_w_ih, 144, 45, tid, nt, F32);
    load_Tp(sNHHp, noise_w_hh, 144, 24, tid, nt, F32);
    load_V (sNBI, noise_b_ih, 144, tid, nt, F32);
    load_V (sNBH, noise_b_hh, 144, tid, nt, F32);
    load_V (sDBI, den_b_ih,  288, tid, nt, F32);
    load_V (sDBH, den_b_hh,  288, tid, nt, F32);
    load_Tp(sOWp, out_w,      22, 48, tid, nt, F32);
    load_V (sOB,  out_b,      22, tid, nt, F32);

    // ---- den weights: per-thread registers, bf16-pair packed ----
    unsigned wih[57];
    unsigned whh[48];
    if (tid < 288) {
        if (F32) {
            const float* p = (const float*)den_w_ih + (size_t)tid * 114;
            #pragma unroll
            for (int i = 0; i < 57; ++i) wih[i] = pack2(p[2 * i], p[2 * i + 1]);
            const float* q = (const float*)den_w_hh + (size_t)tid * 96;
            #pragma unroll
            for (int i = 0; i < 48; ++i) whh[i] = pack2(q[2 * i], q[2 * i + 1]);
        } else {
            const unsigned* p = (const unsigned*)den_w_ih + tid * 57;
            #pragma unroll
            for (int i = 0; i < 57; ++i) wih[i] = p[i];
            const unsigned* q = (const unsigned*)den_w_hh + tid * 48;
            #pragma unroll
            for (int i = 0; i < 48; ++i) whh[i] = q[i];
        }
    } else {
        #pragma unroll
        for (int i = 0; i < 57; ++i) wih[i] = 0u;
        #pragma unroll
        for (int i = 0; i < 48; ++i) whh[i] = 0u;
    }

    // ---- prologue ----
    for (int i = tid; i < 96; i += nt) {
        sR[i] = 0.f; sZ[i] = 0.f; sXN[i] = 0.f; sHN2[i] = 0.f; sHD[i] = 0.f;
    }
    for (int i = tid; i < 90;  i += nt) sNIN[i] = 0.f;
    for (int i = tid; i < 114; i += nt) sDIN[i] = 0.f;
    if (tid < HVAD) { sHV[tid] = 0.f; sTMP[tid] = 0.f; }
    if (tid < HNOI) sHN[tid] = 0.f;
    if (tid < FF) sXT[tid] = F32 ? xbf[tid] : bf2f(xbh[tid]);
    float xreg = 0.f;
    if (tid >= 128 && tid < 128 + FF) {
        int idx = FF + (tid - 128);
        xreg = F32 ? xbf[idx] : bf2f(xbh[idx]);
    }
    __syncthreads();

    for (int t = 0; t < TT; ++t) {
        // ---- stage B: dense(t)  ||  out head(t-1) ----
        if (tid < 24) {
            float a0 = sDB[tid], a1 = 0.f, a2 = 0.f, a3 = 0.f;
            #pragma unroll
            for (int k = 0; k < 40; k += 4) {
                a0 += sDW[(k    ) * 24 + tid] * sXT[k    ];
                a1 += sDW[(k + 1) * 24 + tid] * sXT[k + 1];
                a2 += sDW[(k + 2) * 24 + tid] * sXT[k + 2];
                a3 += sDW[(k + 3) * 24 + tid] * sXT[k + 3];
            }
            a0 += sDW[40 * 24 + tid] * sXT[40];
            a1 += sDW[41 * 24 + tid] * sXT[41];
            sTMP[tid] = tanh_fast((a0 + a1) + (a2 + a3));
        } else if (tid >= 192 && tid < 214) {
            if (t > 0) {
                int o = tid - 192;
                float a0 = sOB[o], a1 = 0.f, a2 = 0.f, a3 = 0.f;
                #pragma unroll
                for (int kp = 0; kp < 48; kp += 2) {
                    unsigned u0 = sOWp[(kp    ) * 22 + o];
                    unsigned u1 = sOWp[(kp + 1) * 22 + o];
                    a0 += unpk_lo(u0) * fmaxf(sHD[2 * kp    ], 0.f);
                    a1 += unpk_hi(u0) * fmaxf(sHD[2 * kp + 1], 0.f);
                    a2 += unpk_lo(u1) * fmaxf(sHD[2 * kp + 2], 0.f);
                    a3 += unpk_hi(u1) * fmaxf(sHD[2 * kp + 3], 0.f);
                }
                size_t oi = ((size_t)b * TT + (t - 1)) * 22 + o;
                float v = sig((a0 + a1) + (a2 + a3));
                if (F32) odf[oi] = v; else odh[oi] = __float2bfloat16(v);
            }
        }
        __syncthreads();

        // ---- stage C: vad gates (72 threads) ----
        if (tid < 72) {
            float a0 = sVBI[tid], a1 = 0.f;
            float h0 = sVBH[tid], h1 = 0.f;
            #pragma unroll
            for (int kp = 0; kp < 12; ++kp) {
                unsigned u1 = sVIHp[kp * 72 + tid];
                a0 += unpk_lo(u1) * sTMP[2 * kp];
                a1 += unpk_hi(u1) * sTMP[2 * kp + 1];
                unsigned u2 = sVHHp[kp * 72 + tid];
                h0 += unpk_lo(u2) * sHV[2 * kp];
                h1 += unpk_hi(u2) * sHV[2 * kp + 1];
            }
            float a = a0 + a1, ah = h0 + h1;
            if (tid < 24)      sR[tid] = sig(a + ah);
            else if (tid < 48) sZ[tid - 24] = sig(a + ah);
            else { sXN[tid - 48] = a; sHN2[tid - 48] = ah; }
        }
        __syncthreads();

        // ---- stage D: vad update || build sNIN = [tmp, vad, x] ----
        if (tid < HVAD) {
            float r = sR[tid], z = sZ[tid];
            float n = tanh_fast(sXN[tid] + r * sHN2[tid]);
            float h = (1.f - z) * n + z * sHV[tid];
            sHV[tid] = h;
            sNIN[24 + tid] = h;
        } else if (tid >= 64 && tid < 88) {
            sNIN[tid - 64] = sTMP[tid - 64];
        } else if (tid >= 96 && tid < 96 + FF) {
            sNIN[48 + (tid - 96)] = sXT[tid - 96];
        }
        __syncthreads();

        // ---- stage E: noise gates (144 threads) ----
        if (tid < 144) {
            float a0 = sNBI[tid], a1 = 0.f, a2 = 0.f, a3 = 0.f;
            #pragma unroll
            for (int kp = 0; kp < 44; kp += 2) {
                unsigned u0 = sNIHp[(kp    ) * 144 + tid];
                unsigned u1 = sNIHp[(kp + 1) * 144 + tid];
                a0 += unpk_lo(u0) * sNIN[2 * kp    ];
                a1 += unpk_hi(u0) * sNIN[2 * kp + 1];
                a2 += unpk_lo(u1) * sNIN[2 * kp + 2];
                a3 += unpk_hi(u1) * sNIN[2 * kp + 3];
            }
            {
                unsigned u = sNIHp[44 * 144 + tid];
                a0 += unpk_lo(u) * sNIN[88];
                a1 += unpk_hi(u) * sNIN[89];
            }
            float h0 = sNBH[tid], h1 = 0.f, h2 = 0.f, h3 = 0.f;
            #pragma unroll
            for (int kp = 0; kp < 24; kp += 2) {
                unsigned u0 = sNHHp[(kp    ) * 144 + tid];
                unsigned u1 = sNHHp[(kp + 1) * 144 + tid];
                h0 += unpk_lo(u0) * sHN[2 * kp    ];
                h1 += unpk_hi(u0) * sHN[2 * kp + 1];
                h2 += unpk_lo(u1) * sHN[2 * kp + 2];
                h3 += unpk_hi(u1) * sHN[2 * kp + 3];
            }
            float a = (a0 + a1) + (a2 + a3), ah = (h0 + h1) + (h2 + h3);
            if (tid < 48)      sR[tid] = sig(a + ah);
            else if (tid < 96) sZ[tid - 48] = sig(a + ah);
            else { sXN[tid - 96] = a; sHN2[tid - 96] = ah; }
        }
        __syncthreads();

        // ---- stage F: noise update || build sDIN = [vad, relu(noise), x] ----
        if (tid < HNOI) {
            float r = sR[tid], z = sZ[tid];
            float n = tanh_fast(sXN[tid] + r * sHN2[tid]);
            float h = (1.f - z) * n + z * sHN[tid];
            sHN[tid] = h;
            sDIN[24 + tid] = fmaxf(h, 0.f);
        } else if (tid >= 64 && tid < 88) {
            sDIN[tid - 64] = sHV[tid - 64];
        } else if (tid >= 96 && tid < 96 + FF) {
            sDIN[72 + (tid - 96)] = sXT[tid - 96];
        }
        __syncthreads();

        // ---- stage G: den gates (288 threads) ----
        if (tid < 288) {
            float a0 = sDBI[tid], a1 = 0.f, a2 = 0.f, a3 = 0.f;
            #pragma unroll
            for (int p = 0; p < 56; p += 2) {
                unsigned u0 = wih[p], u1 = wih[p + 1];
                a0 += unpk_lo(u0) * sDIN[2 * p    ];
                a1 += unpk_hi(u0) * sDIN[2 * p + 1];
                a2 += unpk_lo(u1) * sDIN[2 * p + 2];
                a3 += unpk_hi(u1) * sDIN[2 * p + 3];
            }
            {
                unsigned u = wih[56];
                a0 += unpk_lo(u) * sDIN[112];
                a1 += unpk_hi(u) * sDIN[113];
            }
            float h0 = sDBH[tid], h1 = 0.f, h2 = 0.f, h3 = 0.f;
            #pragma unroll
            for (int p = 0; p < 48; p += 2) {
                unsigned u0 = whh[p], u1 = whh[p + 1];
                h0 += unpk_lo(u0) * sHD[2 * p    ];
                h1 += unpk_hi(u0) * sHD[2 * p + 1];
                h2 += unpk_lo(u1) * sHD[2 * p + 2];
                h3 += unpk_hi(u1) * sHD[2 * p + 3];
            }
            float a = (a0 + a1) + (a2 + a3), ah = (h0 + h1) + (h2 + h3);
            if (tid < 96)       sR[tid] = sig(a + ah);
            else if (tid < 192) sZ[tid - 96] = sig(a + ah);
            else { sXN[tid - 192] = a; sHN2[tid - 192] = ah; }
        }
        __syncthreads();

        // ---- stage H: den update || x(t+1) staging || vad_out(t) ----
        if (tid < HDEN) {
            float r = sR[tid], z = sZ[tid];
            float n = tanh_fast(sXN[tid] + r * sHN2[tid]);
            sHD[tid] = (1.f - z) * n + z * sHD[tid];
        } else if (tid >= 128 && tid < 128 + FF) {
            if (t + 1 < TT) {
                sXT[tid - 128] = xreg;
                int t2 = (t + 2 < TT) ? (t + 2) : (TT - 1);
                int idx = t2 * FF + (tid - 128);
                xreg = F32 ? xbf[idx] : bf2f(xbh[idx]);
            }
        } else if (tid == 214) {
            float a = sVOB[0];
            #pragma unroll
            for (int k = 0; k < 24; ++k) a += sVOW[k] * sHV[k];
            size_t oi = (size_t)b * TT + t;
            float v = sig(a);
            if (F32) ovf[oi] = v; else ovh[oi] = __float2bfloat16(v);
        }
        __syncthreads();
    }

    // ---- epilogue: out head for t = T-1 ----
    if (tid >= 192 && tid < 214) {
        int o = tid - 192;
        float a0 = sOB[o], a1 = 0.f, a2 = 0.f, a3 = 0.f;
        #pragma unroll
        for (int kp = 0; kp < 48; kp += 2) {
            unsigned u0 = sOWp[(kp    ) * 22 + o];
            unsigned u1 = sOWp[(kp + 1) * 22 + o];
            a0 += unpk_lo(u0) * fmaxf(sHD[2 * kp    ], 0.f);
            a1 += unpk_hi(u0) * fmaxf(sHD[2 * kp + 1], 0.f);
            a2 += unpk_lo(u1) * fmaxf(sHD[2 * kp + 2], 0.f);
            a3 += unpk_hi(u1) * fmaxf(sHD[2 * kp + 3], 0.f);
        }
        size_t oi = ((size_t)b * TT + (TT - 1)) * 22 + o;
        float v = sig((a0 + a1) + (a2 + a3));
        if (F32) odf[oi] = v; else odh[oi] = __float2bfloat16(v);
    }
}

extern "C" void kernel_launch(void* const* d_in, const int* in_sizes, int n_in,
                              void* d_out, int out_size, void* d_ws, size_t ws_size,
                              hipStream_t stream) {
    hipLaunchKernelGGL(rnn_fused, dim3(BB), dim3(NTHREADS), 0, stream,
                       d_in[0], d_in[1], d_in[2],
                       d_in[3], d_in[4], d_in[5], d_in[6],
                       d_in[7], d_in[8],
                       d_in[9], d_in[10], d_in[11], d_in[12],
                       d_in[13], d_in[14], d_in[15], d_in[16],
                       d_in[17], d_in[18], d_out);
}

// Round 6
// 10037.325 us; speedup vs baseline: 10.5873x; 10.5873x over previous
//
#include <hip/hip_runtime.h>
#include <hip/hip_bf16.h>

#define BB 256
#define TT 2000
#define FF 42
#define NTHREADS 640

__device__ __forceinline__ float bf2f(__hip_bfloat16 v) { return __bfloat162float(v); }
__device__ __forceinline__ float sig(float x) { return 1.0f / (1.0f + __expf(-x)); }
__device__ __forceinline__ float tanh_fast(float x) {
    float e = __expf(2.0f * x);
    return 1.0f - 2.0f / (e + 1.0f);
}
__device__ __forceinline__ float unpk_lo(unsigned u) {
    union { unsigned u; float f; } c; c.u = u << 16; return c.f;
}
__device__ __forceinline__ float unpk_hi(unsigned u) {
    union { unsigned u; float f; } c; c.u = u & 0xffff0000u; return c.f;
}
// fp32 -> bf16 bits, round-to-nearest-even
__device__ __forceinline__ unsigned f2bfbits(float f) {
    union { float f; unsigned u; } c; c.f = f;
    unsigned r = c.u + 0x7FFFu + ((c.u >> 16) & 1u);
    return r >> 16;
}
__device__ __forceinline__ unsigned pack2(float a, float b) {
    return f2bfbits(a) | (f2bfbits(b) << 16);
}
__device__ __forceinline__ float gld(const void* p, int i, bool f32) {
    return f32 ? ((const float*)p)[i] : bf2f(((const __hip_bfloat16*)p)[i]);
}

// packed bf16 weight row (LDS) · fp32 input (LDS, float2 reads), 2-way accs
template<int NW>
__device__ __forceinline__ float dot_w2(const unsigned* __restrict__ w,
                                        const float* __restrict__ in, float acc) {
    const float2* in2 = (const float2*)in;
    float a0 = acc, a1 = 0.f;
    #pragma unroll
    for (int i = 0; i < NW; ++i) {
        unsigned u = w[i];
        float2 d = in2[i];
        a0 = fmaf(unpk_lo(u), d.x, a0);
        a1 = fmaf(unpk_hi(u), d.y, a1);
    }
    return a0 + a1;
}
// packed bf16 weight row (registers) · fp32 input (LDS float2)
template<int NW>
__device__ __forceinline__ float dot_reg2(const unsigned (&w)[57],
                                          const float* __restrict__ in, float acc) {
    const float2* in2 = (const float2*)in;
    float a0 = acc, a1 = 0.f;
    #pragma unroll
    for (int i = 0; i < NW; ++i) {
        unsigned u = w[i];
        float2 d = in2[i];
        a0 = fmaf(unpk_lo(u), d.x, a0);
        a1 = fmaf(unpk_hi(u), d.y, a1);
    }
    return a0 + a1;
}

// W[O][K] row-major -> dst[o*S + kp] packed bf16 pairs (Kw = K/2, S = row stride)
__device__ void load_rows(unsigned* dst, const void* src, int O, int Kw, int K, int S,
                          int tid, int nt, bool f32) {
    for (int i = tid; i < O * Kw; i += nt) {
        int o = i / Kw, kp = i - o * Kw;
        dst[o * S + kp] = pack2(gld(src, o * K + 2 * kp, f32),
                                gld(src, o * K + 2 * kp + 1, f32));
    }
}
__device__ void load_V(float* dst, const void* src, int n, int tid, int nt, bool f32) {
    for (int i = tid; i < n; i += nt) dst[i] = gld(src, i, f32);
}

__global__ __launch_bounds__(NTHREADS, 1)
void rnn_fused(const void* __restrict__ x,
               const void* __restrict__ dense_w, const void* __restrict__ dense_b,
               const void* __restrict__ vad_w_ih, const void* __restrict__ vad_w_hh,
               const void* __restrict__ vad_b_ih, const void* __restrict__ vad_b_hh,
               const void* __restrict__ vad_out_w, const void* __restrict__ vad_out_b,
               const void* __restrict__ noise_w_ih, const void* __restrict__ noise_w_hh,
               const void* __restrict__ noise_b_ih, const void* __restrict__ noise_b_hh,
               const void* __restrict__ den_w_ih, const void* __restrict__ den_w_hh,
               const void* __restrict__ den_b_ih, const void* __restrict__ den_b_hh,
               const void* __restrict__ out_w, const void* __restrict__ out_b,
               void* __restrict__ d_out) {
    // ---- LDS (~62.3 KiB): packed bf16 weights, fp32 state/activations ----
    __shared__ __align__(16) unsigned sDWp[24 * 21];   // dense rows
    __shared__ __align__(16) unsigned sVIHp[72 * 13];  // vad ih rows (12w, stride 13)
    __shared__ __align__(16) unsigned sVHHp[72 * 13];
    __shared__ __align__(16) unsigned sNIHp[144 * 45]; // noise ih rows
    __shared__ __align__(16) unsigned sNHHp[144 * 25]; // noise hh rows (24w, stride 25)
    __shared__ __align__(16) unsigned sOWp[22 * 49];   // out rows (48w, stride 49)
    __shared__ unsigned sVOWp[12];
    __shared__ float sDB[24], sVBI[72], sVBH[72], sNBI[144], sNBH[144], sOB[22], sVOB[1];
    __shared__ __align__(16) float sXT[44];    // x(t) fp32 (+pad)
    __shared__ __align__(16) float sTMP[24];   // dense out
    __shared__ __align__(16) float sHV[24];    // h_vad (fp32 master)
    __shared__ __align__(16) float sHN[48];    // h_noise
    __shared__ __align__(16) float sHD[96];    // h_den
    __shared__ __align__(16) float sHR[96];    // relu(h_den)
    __shared__ __align__(16) float sNIN[92];   // [tmp,vad,x] (+pad)
    __shared__ __align__(16) float sDIN[116];  // [vad,relu(noise),x] (+pad)
    __shared__ float sVPI[72], sVPH[72];       // vad partials
    __shared__ float sNPI[144], sNPH[144];     // noise partials
    __shared__ float sGI[288], sGH[288];       // den partials
    __shared__ int sBad;

    const int tid = threadIdx.x;
    const int b = blockIdx.x;
    const int nt = NTHREADS;

    // ---- dtype detection (validated rounds 3/4) ----
    if (tid == 0) sBad = 0;
    __syncthreads();
    {
        const unsigned* w = (const unsigned*)dense_w;
        for (int i = tid; i < 500; i += nt) {
            float av = fabsf(unpk_lo(w[i]));
            if (!(av <= 1e3f)) { atomicAdd(&sBad, 1); break; }
        }
    }
    __syncthreads();
    const bool F32 = (sBad > 0);

    const float* xbf = (const float*)x + (size_t)b * TT * FF;
    const __hip_bfloat16* xbh = (const __hip_bfloat16*)x + (size_t)b * TT * FF;
    float* odf = (float*)d_out;
    __hip_bfloat16* odh = (__hip_bfloat16*)d_out;
    float* ovf = odf + (size_t)BB * TT * 22;
    __hip_bfloat16* ovh = odh + (size_t)BB * TT * 22;

    // ---- load LDS weights ----
    load_rows(sDWp,  dense_w,    24, 21, 42, 21, tid, nt, F32);
    load_rows(sVIHp, vad_w_ih,   72, 12, 24, 13, tid, nt, F32);
    load_rows(sVHHp, vad_w_hh,   72, 12, 24, 13, tid, nt, F32);
    load_rows(sNIHp, noise_w_ih, 144, 45, 90, 45, tid, nt, F32);
    load_rows(sNHHp, noise_w_hh, 144, 24, 48, 25, tid, nt, F32);
    load_rows(sOWp,  out_w,      22, 48, 96, 49, tid, nt, F32);
    if (tid < 12) sVOWp[tid] = pack2(gld(vad_out_w, 2 * tid, F32),
                                     gld(vad_out_w, 2 * tid + 1, F32));
    load_V(sDB,  dense_b,    24, tid, nt, F32);
    load_V(sVBI, vad_b_ih,   72, tid, nt, F32);
    load_V(sVBH, vad_b_hh,   72, tid, nt, F32);
    load_V(sNBI, noise_b_ih, 144, tid, nt, F32);
    load_V(sNBH, noise_b_hh, 144, tid, nt, F32);
    load_V(sOB,  out_b,      22, tid, nt, F32);
    if (tid == 0) sVOB[0] = gld(vad_out_b, 0, F32);

    // ---- den weights in registers: ih rows on tid 0..287 (57 words),
    //      hh rows on tid 320..607 (48 words). Waves don't mix roles. ----
    unsigned wden[57];
    float bDen = 0.f;
    if (tid < 288) {
        #pragma unroll
        for (int i = 0; i < 57; ++i)
            wden[i] = pack2(gld(den_w_ih, tid * 114 + 2 * i, F32),
                            gld(den_w_ih, tid * 114 + 2 * i + 1, F32));
        bDen = gld(den_b_ih, tid, F32);
    } else if (tid >= 320 && tid < 608) {
        int o = tid - 320;
        #pragma unroll
        for (int i = 0; i < 48; ++i)
            wden[i] = pack2(gld(den_w_hh, o * 96 + 2 * i, F32),
                            gld(den_w_hh, o * 96 + 2 * i + 1, F32));
        #pragma unroll
        for (int i = 48; i < 57; ++i) wden[i] = 0u;
        bDen = gld(den_b_hh, o, F32);
    } else {
        #pragma unroll
        for (int i = 0; i < 57; ++i) wden[i] = 0u;
    }

    // ---- prologue: zero state, stage x(0), prefetch x(1) ----
    for (int i = tid; i < 24; i += nt) { sHV[i] = 0.f; sTMP[i] = 0.f; }
    for (int i = tid; i < 48; i += nt) sHN[i] = 0.f;
    for (int i = tid; i < 96; i += nt) { sHD[i] = 0.f; sHR[i] = 0.f; }
    if (tid < 2) { sXT[42 + tid] = 0.f; sNIN[90 + tid] = 0.f; sDIN[114 + tid] = 0.f; }
    float xreg = 0.f;
    if (tid >= 128 && tid < 128 + FF) {
        int j = tid - 128;
        float v = F32 ? xbf[j] : bf2f(xbh[j]);
        sXT[j] = v;
        sNIN[48 + j] = v;
        sDIN[72 + j] = v;
        xreg = F32 ? xbf[FF + j] : bf2f(xbh[FF + j]);
    }
    __syncthreads();

    for (int t = 0; t < TT; ++t) {
        // ---- stage B: dense(t) [wave 0] || out head(t-1) [wave 1] ----
        if (tid < 24) {
            float v = tanh_fast(dot_w2<21>(sDWp + tid * 21, sXT, sDB[tid]));
            sTMP[tid] = v;
            sNIN[tid] = v;
        } else if (tid >= 64 && tid < 86) {
            if (t > 0) {
                int o = tid - 64;
                float a = dot_w2<48>(sOWp + o * 49, sHR, sOB[o]);
                size_t oi = ((size_t)b * TT + (t - 1)) * 22 + o;
                float v = sig(a);
                if (F32) odf[oi] = v; else odh[oi] = __float2bfloat16(v);
            }
        }
        __syncthreads();

        // ---- stage C: vad partials — ih tid 0..71, hh tid 128..199 ----
        if (tid < 72) {
            sVPI[tid] = dot_w2<12>(sVIHp + tid * 13, sTMP, sVBI[tid]);
        } else if (tid >= 128 && tid < 200) {
            int o = tid - 128;
            sVPH[o] = dot_w2<12>(sVHHp + o * 13, sHV, sVBH[o]);
        }
        __syncthreads();

        // ---- stage D: vad update ----
        if (tid < 24) {
            float r = sig(sVPI[tid] + sVPH[tid]);
            float z = sig(sVPI[24 + tid] + sVPH[24 + tid]);
            float n = tanh_fast(sVPI[48 + tid] + r * sVPH[48 + tid]);
            float h = (1.f - z) * n + z * sHV[tid];
            sHV[tid] = h;
            sNIN[24 + tid] = h;
            sDIN[tid] = h;
        }
        __syncthreads();

        // ---- stage E: noise partials — ih tid 0..143, hh tid 192..335 ----
        if (tid < 144) {
            sNPI[tid] = dot_w2<45>(sNIHp + tid * 45, sNIN, sNBI[tid]);
        } else if (tid >= 192 && tid < 336) {
            int o = tid - 192;
            sNPH[o] = dot_w2<24>(sNHHp + o * 25, sHN, sNBH[o]);
        }
        __syncthreads();

        // ---- stage F: noise update ----
        if (tid < 48) {
            float r = sig(sNPI[tid] + sNPH[tid]);
            float z = sig(sNPI[48 + tid] + sNPH[48 + tid]);
            float n = tanh_fast(sNPI[96 + tid] + r * sNPH[96 + tid]);
            float h = (1.f - z) * n + z * sHN[tid];
            sHN[tid] = h;
            sDIN[24 + tid] = fmaxf(h, 0.f);
        }
        __syncthreads();

        // ---- stage G: den partials — ih tid 0..287, hh tid 320..607 ----
        if (tid < 288) {
            sGI[tid] = dot_reg2<57>(wden, sDIN, bDen);
        } else if (tid >= 320 && tid < 608) {
            sGH[tid - 320] = dot_reg2<48>(wden, sHD, bDen);
        }
        __syncthreads();

        // ---- stage H: den update [waves 0-1] || x staging [wave 2] || vad_out [wave 3] ----
        if (tid < 96) {
            float r = sig(sGI[tid] + sGH[tid]);
            float z = sig(sGI[96 + tid] + sGH[96 + tid]);
            float n = tanh_fast(sGI[192 + tid] + r * sGH[192 + tid]);
            float h = (1.f - z) * n + z * sHD[tid];
            sHD[tid] = h;
            sHR[tid] = fmaxf(h, 0.f);
        } else if (tid >= 128 && tid < 128 + FF) {
            if (t + 1 < TT) {
                int j = tid - 128;
                sXT[j] = xreg;
                sNIN[48 + j] = xreg;
                sDIN[72 + j] = xreg;
                int t2 = (t + 2 < TT) ? (t + 2) : (TT - 1);
                xreg = F32 ? xbf[t2 * FF + j] : bf2f(xbh[t2 * FF + j]);
            }
        } else if (tid == 200) {
            float a = sVOB[0];
            const float2* hv2 = (const float2*)sHV;
            #pragma unroll
            for (int i = 0; i < 12; ++i) {
                unsigned u = sVOWp[i];
                float2 d = hv2[i];
                a = fmaf(unpk_lo(u), d.x, a);
                a = fmaf(unpk_hi(u), d.y, a);
            }
            size_t oi = (size_t)b * TT + t;
            float v = sig(a);
            if (F32) ovf[oi] = v; else ovh[oi] = __float2bfloat16(v);
        }
        __syncthreads();
    }

    // ---- epilogue: out head for t = TT-1 ----
    if (tid >= 64 && tid < 86) {
        int o = tid - 64;
        float a = dot_w2<48>(sOWp + o * 49, sHR, sOB[o]);
        size_t oi = ((size_t)b * TT + (TT - 1)) * 22 + o;
        float v = sig(a);
        if (F32) odf[oi] = v; else odh[oi] = __float2bfloat16(v);
    }
}

extern "C" void kernel_launch(void* const* d_in, const int* in_sizes, int n_in,
                              void* d_out, int out_size, void* d_ws, size_t ws_size,
                              hipStream_t stream) {
    hipLaunchKernelGGL(rnn_fused, dim3(BB), dim3(NTHREADS), 0, stream,
                       d_in[0], d_in[1], d_in[2],
                       d_in[3], d_in[4], d_in[5], d_in[6],
                       d_in[7], d_in[8],
                       d_in[9], d_in[10], d_in[11], d_in[12],
                       d_in[13], d_in[14], d_in[15], d_in[16],
                       d_in[17], d_in[18], d_out);
}